// Round 1
// baseline (580.246 us; speedup 1.0000x reference)
//
#include <hip/hip_runtime.h>
#include <hip/hip_bf16.h>

// Problem constants (from reference): B=256, C=64, T=4096, SNR_DB=10 -> 10^(-1)=0.1
// Layouts (all contiguous fp32, identical row layout):
//   x         : [B,1,C,T]  -> row r = b*C+c, offset r*T
//   noise_unit: [B,C,T]    -> same row offsets
//   out       : [B,1,C,T]  -> same
// One block per (b,c) row: 256 threads x 16 elems (4x float4) = 4096 = T.
// x row held in registers across the reduction so it is fetched from HBM once.

#define T_LEN 4096
#define C_CH  64
#define THREADS 256
#define ELEMS_PER_THREAD 4  // float4 chunks per thread: 4 * 4 * 256 = 4096 floats

__global__ __launch_bounds__(THREADS) void gaussian_noise_kernel(
    const float* __restrict__ x,
    const float* __restrict__ noise_unit,
    const int* __restrict__ mask,
    float* __restrict__ out)
{
    const int row = blockIdx.x;          // b*C + c
    const int b = row / C_CH;
    const long long base = (long long)row * T_LEN;

    const float4* __restrict__ x4 = (const float4*)(x + base);
    const float4* __restrict__ n4 = (const float4*)(noise_unit + base);
    float4* __restrict__ o4 = (float4*)(out + base);

    const int tid = threadIdx.x;

    // Load x row into registers, accumulate partial sum.
    float4 xa[ELEMS_PER_THREAD];
    float sum = 0.0f;
#pragma unroll
    for (int i = 0; i < ELEMS_PER_THREAD; ++i) {
        xa[i] = x4[tid + i * THREADS];
        sum += (xa[i].x + xa[i].y) + (xa[i].z + xa[i].w);
    }

    // Wave (64-lane) shuffle reduction.
#pragma unroll
    for (int off = 32; off > 0; off >>= 1)
        sum += __shfl_down(sum, off, 64);

    __shared__ float wsum[THREADS / 64];
    const int lane = tid & 63;
    const int wid = tid >> 6;
    if (lane == 0) wsum[wid] = sum;
    __syncthreads();

    const float tot = (wsum[0] + wsum[1]) + (wsum[2] + wsum[3]);
    const float p_sig = fabsf(tot * (1.0f / (float)T_LEN));
    const float noise_std = sqrtf(p_sig * 0.1f);   // 10^(-SNR_DB/10) = 0.1
    const float g = (mask[b] != 0) ? noise_std : 0.0f;

    // out = x + noise_unit * g
#pragma unroll
    for (int i = 0; i < ELEMS_PER_THREAD; ++i) {
        const float4 n = n4[tid + i * THREADS];
        float4 o;
        o.x = fmaf(n.x, g, xa[i].x);
        o.y = fmaf(n.y, g, xa[i].y);
        o.z = fmaf(n.z, g, xa[i].z);
        o.w = fmaf(n.w, g, xa[i].w);
        o4[tid + i * THREADS] = o;
    }
}

extern "C" void kernel_launch(void* const* d_in, const int* in_sizes, int n_in,
                              void* d_out, int out_size, void* d_ws, size_t ws_size,
                              hipStream_t stream) {
    const float* x          = (const float*)d_in[0];
    const float* noise_unit = (const float*)d_in[1];
    const int*   mask       = (const int*)d_in[2];   // bool [B] materialized as int32
    float* out = (float*)d_out;

    const int n_rows = 256 * C_CH;  // B * C = 16384 blocks
    gaussian_noise_kernel<<<n_rows, THREADS, 0, stream>>>(x, noise_unit, mask, out);
}